// Round 12
// baseline (164.169 us; speedup 1.0000x reference)
//
#include <hip/hip_runtime.h>

#define NROWS 4096
#define DIM   128
#define KCLS  4
#define NBLK  1056               // sum_{tJ=0..31} (2*tJ+2)
#define MARGIN_F 0.02f
#define EPS_F    1e-12f

typedef unsigned short ushort_t;
typedef unsigned int   uint_t;
typedef __attribute__((ext_vector_type(8)))  short bf16x8;
typedef __attribute__((ext_vector_type(16))) float f32x16;

__device__ __forceinline__ ushort_t rne_bf16(float v, float& back) {
    uint_t u = __float_as_uint(v);
    uint_t r = (u + 0x7fffu + ((u >> 16) & 1u)) >> 16;
    back = __uint_as_float(r << 16);
    return (ushort_t)r;
}

__device__ __forceinline__ bf16x8 pack8(const ushort_t* h) {
    bf16x8 v;
#pragma unroll
    for (int e = 0; e < 8; ++e) v[e] = (short)h[e];
    return v;
}

__device__ __forceinline__ float fsqrt(float x) {
    float r;
    asm("v_sqrt_f32 %0, %1" : "=v"(r) : "v"(x));
    return r;
}

// blocks ordered tJ ascending, ti in 0..2tJ+1; start(tJ)=tJ*(tJ+1)
__device__ __forceinline__ void blk_decode(int bid, int& ti, int& tJ) {
    tJ = (int)((sqrtf((float)(4 * bid + 1)) - 1.0f) * 0.5f);
    while ((tJ + 1) * (tJ + 2) <= bid) ++tJ;
    while (tJ * (tJ + 1) > bid) --tJ;
    ti = bid - tJ * (tJ + 1);
}

#define LD(dst, base, off) dst = *(const bf16x8*)((base) + (off))

// ---------------- kernel 1: wave-per-class prep (validated R9/R10) ----------
__global__ __launch_bounds__(256) void k_prep(
    const float* __restrict__ x,
    float4* __restrict__ spd,
    ushort_t* __restrict__ xf,
    uint_t* __restrict__ imask, uint_t* __restrict__ jmask,
    uint_t* __restrict__ counter,
    float* __restrict__ posp)
{
    if (blockIdx.x == 0) {
        const int tt = threadIdx.x;
        if (tt < 128) imask[tt] = 0u; else jmask[tt - 128] = 0u;
        if (tt == 0) *counter = 0u;
    }
    const int wave = threadIdx.x >> 6, lane = threadIdx.x & 63;
    const int cls  = (blockIdx.x << 2) + wave;
    const int r0   = lane >> 4;
    const int cseg = lane & 15;
    const int row  = (cls << 2) + r0;

    const float4* rp = (const float4*)(x + (size_t)row * DIM + (cseg << 3));
    const float4 v0 = rp[0], v1 = rp[1];
    float vs[8] = {v0.x, v0.y, v0.z, v0.w, v1.x, v1.y, v1.z, v1.w};

    float sq = 0.f;
#pragma unroll
    for (int e = 0; e < 8; ++e) sq = fmaf(vs[e], vs[e], sq);
#pragma unroll
    for (int off = 1; off < 16; off <<= 1) sq += __shfl_xor(sq, off, 16);

    float sq4[4];
#pragma unroll
    for (int s = 0; s < 4; ++s) sq4[s] = __shfl(sq, (s << 4) | cseg);

    float dl[3];
#pragma unroll
    for (int delta = 1; delta <= 3; ++delta) {
        const int p = r0 ^ delta;
        float dot = 0.f;
#pragma unroll
        for (int e = 0; e < 8; ++e) {
            const float o = __shfl(vs[e], (p << 4) | cseg);
            dot = fmaf(vs[e], o, dot);
        }
#pragma unroll
        for (int off = 1; off < 16; off <<= 1) dot += __shfl_xor(dot, off, 16);
        dl[delta - 1] = fsqrt(fmaxf(sq4[r0] + sq4[p] - 2.f * dot, EPS_F));
    }
    float po[3];
#pragma unroll
    for (int o = 0; o < 3; ++o) {
        const int s = o + (o >= r0 ? 1 : 0);
        const int d = r0 ^ s;
        po[o] = (d == 1) ? dl[0] : (d == 2) ? dl[1] : dl[2];
    }
    if (cseg == 0) spd[row] = make_float4(sq4[r0], po[0], po[1], po[2]);

    // per-block positive-distance partial (for the fused finalize)
    float ppart = (cseg == 0) ? (po[0] + po[1] + po[2]) : 0.f;
#pragma unroll
    for (int off = 32; off; off >>= 1) ppart += __shfl_down(ppart, off);
    __shared__ float pblk[4];
    if (lane == 0) pblk[wave] = ppart;
    __syncthreads();
    if (threadIdx.x == 0)
        posp[blockIdx.x] = pblk[0] + pblk[1] + pblk[2] + pblk[3];

    ushort_t hs[8], ls[8];
#pragma unroll
    for (int e = 0; e < 8; ++e) {
        float back, d_;
        hs[e] = rne_bf16(vs[e], back);
        ls[e] = rne_bf16(vs[e] - back, d_);
    }
    const int band = row >> 5, L = row & 31, cb = cseg >> 1, sf = cseg & 1;
    ushort_t* dst = xf + ((size_t)((band << 3) + cb) << 1) * 512
                       + (((sf << 5) + L) << 3);
    *(bf16x8*)dst         = pack8(hs);
    *(bf16x8*)(dst + 512) = pack8(ls);
}

// ---------------- kernel 2: MFMA Gram + hinge + fused finalize -------------
__global__ __launch_bounds__(256, 4) void k_tiles(
    const ushort_t* __restrict__ xf,
    const float4* __restrict__ spd,
    uint_t* __restrict__ imask, uint_t* __restrict__ jmask,
    float4* __restrict__ partial,
    uint_t* __restrict__ counter,
    const float* __restrict__ posp,
    float* __restrict__ out)
{
    int ti, tJ;
    blk_decode((int)blockIdx.x, ti, tJ);

    const int t = threadIdx.x, wave = t >> 6, lane = t & 63;
    const int wr = wave >> 1, wc = wave & 1;
    const int col = lane & 31, hi = lane >> 5;
    const int ibase = ti << 6;
    const int tj64 = (tJ << 1) + wc;
    const bool active   = (tj64 >= ti);
    const bool anchor_j = (tj64 > ti);
    const int jb  = (tJ << 2) + (wc << 1);
    const int jg0 = (jb << 5) + col;
    const int jg1 = jg0 + 32;

    __shared__ float4 spd_i[64];
    __shared__ float4 wpart[4];
    __shared__ uint_t lastflag;

    // T14: issue row-spd load now, consume after the MFMA phase
    float4 myspd;
    if (t < 64) myspd = spd[ibase + t];
    const float4 sj0 = spd[jg0];
    const float4 sj1 = spd[jg1];

    const ushort_t* pa  = xf + (size_t)((ti << 1) + wr) * 8192 + lane * 8;
    const ushort_t* pb0 = xf + (size_t)jb * 8192 + lane * 8;
    const ushort_t* pb1 = pb0 + 8192;

    f32x16 acc0, acc1;
#pragma unroll
    for (int r = 0; r < 16; ++r) { acc0[r] = 0.f; acc1[r] = 0.f; }

    // 2-deep named-register double-buffered MFMA loop
    bf16x8 A0h, A0l, B0h, B0l, C0h, C0l;
    bf16x8 A1h, A1l, B1h, B1l, C1h, C1l;
    LD(A0h, pa, 0);   LD(A0l, pa, 512);
    LD(B0h, pb0, 0);  LD(B0l, pb0, 512);
    LD(C0h, pb1, 0);  LD(C0l, pb1, 512);
#pragma unroll
    for (int c = 0; c < 8; c += 2) {
        LD(A1h, pa,  (c + 1) * 1024); LD(A1l, pa,  (c + 1) * 1024 + 512);
        LD(B1h, pb0, (c + 1) * 1024); LD(B1l, pb0, (c + 1) * 1024 + 512);
        LD(C1h, pb1, (c + 1) * 1024); LD(C1l, pb1, (c + 1) * 1024 + 512);
        acc0 = __builtin_amdgcn_mfma_f32_32x32x16_bf16(A0h, B0h, acc0, 0, 0, 0);
        acc1 = __builtin_amdgcn_mfma_f32_32x32x16_bf16(A0h, C0h, acc1, 0, 0, 0);
        acc0 = __builtin_amdgcn_mfma_f32_32x32x16_bf16(A0h, B0l, acc0, 0, 0, 0);
        acc1 = __builtin_amdgcn_mfma_f32_32x32x16_bf16(A0h, C0l, acc1, 0, 0, 0);
        acc0 = __builtin_amdgcn_mfma_f32_32x32x16_bf16(A0l, B0h, acc0, 0, 0, 0);
        acc1 = __builtin_amdgcn_mfma_f32_32x32x16_bf16(A0l, C0h, acc1, 0, 0, 0);
        if (c + 2 < 8) {
            LD(A0h, pa,  (c + 2) * 1024); LD(A0l, pa,  (c + 2) * 1024 + 512);
            LD(B0h, pb0, (c + 2) * 1024); LD(B0l, pb0, (c + 2) * 1024 + 512);
            LD(C0h, pb1, (c + 2) * 1024); LD(C0l, pb1, (c + 2) * 1024 + 512);
        }
        acc0 = __builtin_amdgcn_mfma_f32_32x32x16_bf16(A1h, B1h, acc0, 0, 0, 0);
        acc1 = __builtin_amdgcn_mfma_f32_32x32x16_bf16(A1h, C1h, acc1, 0, 0, 0);
        acc0 = __builtin_amdgcn_mfma_f32_32x32x16_bf16(A1h, B1l, acc0, 0, 0, 0);
        acc1 = __builtin_amdgcn_mfma_f32_32x32x16_bf16(A1h, C1l, acc1, 0, 0, 0);
        acc0 = __builtin_amdgcn_mfma_f32_32x32x16_bf16(A1l, B1h, acc0, 0, 0, 0);
        acc1 = __builtin_amdgcn_mfma_f32_32x32x16_bf16(A1l, C1h, acc1, 0, 0, 0);
    }

    if (t < 64) spd_i[t] = myspd;
    __syncthreads();

    float ts = 0.f, ns = 0.f, cntf = 0.f;
    uint_t iam = 0, jany0 = 0, jany1 = 0;

    if (active) {
        const int jcls0 = jg0 >> 2, jcls1 = jg1 >> 2;
        const float nsw = anchor_j ? 2.f : 1.f;
#pragma unroll
        for (int r = 0; r < 16; ++r) {
            const int src = (r & 3) + ((r >> 2) << 3) + (hi << 2);
            const float4 si = spd_i[(wr << 5) + src];
            const int icls = (ibase + (wr << 5) + src) >> 2;
            {   // band 0
                const float dd = fsqrt(fmaxf(si.x + sj0.x - 2.f * acc0[r], EPS_F));
                const bool skip = !anchor_j && (icls == jcls0);
                if (!skip) {
                    ns += nsw * dd;
                    uint_t v = 0; float h;
                    h = si.y + MARGIN_F - dd; if (h > 0.f) { ts += h; cntf += 1.f; v = 1u; }
                    h = si.z + MARGIN_F - dd; if (h > 0.f) { ts += h; cntf += 1.f; v = 1u; }
                    h = si.w + MARGIN_F - dd; if (h > 0.f) { ts += h; cntf += 1.f; v = 1u; }
                    iam |= v << r;
                    if (anchor_j) {
                        h = sj0.y + MARGIN_F - dd; if (h > 0.f) { ts += h; cntf += 1.f; jany0 = 1u; }
                        h = sj0.z + MARGIN_F - dd; if (h > 0.f) { ts += h; cntf += 1.f; jany0 = 1u; }
                        h = sj0.w + MARGIN_F - dd; if (h > 0.f) { ts += h; cntf += 1.f; jany0 = 1u; }
                    }
                }
            }
            {   // band 1
                const float dd = fsqrt(fmaxf(si.x + sj1.x - 2.f * acc1[r], EPS_F));
                const bool skip = !anchor_j && (icls == jcls1);
                if (!skip) {
                    ns += nsw * dd;
                    uint_t v = 0; float h;
                    h = si.y + MARGIN_F - dd; if (h > 0.f) { ts += h; cntf += 1.f; v = 1u; }
                    h = si.z + MARGIN_F - dd; if (h > 0.f) { ts += h; cntf += 1.f; v = 1u; }
                    h = si.w + MARGIN_F - dd; if (h > 0.f) { ts += h; cntf += 1.f; v = 1u; }
                    iam |= v << r;
                    if (anchor_j) {
                        h = sj1.y + MARGIN_F - dd; if (h > 0.f) { ts += h; cntf += 1.f; jany1 = 1u; }
                        h = sj1.z + MARGIN_F - dd; if (h > 0.f) { ts += h; cntf += 1.f; jany1 = 1u; }
                        h = sj1.w + MARGIN_F - dd; if (h > 0.f) { ts += h; cntf += 1.f; jany1 = 1u; }
                    }
                }
            }
        }

        uint_t iam_all = iam;
#pragma unroll
        for (int off = 1; off < 32; off <<= 1)
            iam_all |= __shfl_xor(iam_all, off);
        uint_t rowmask = 0;
#pragma unroll
        for (int r = 0; r < 16; ++r)
            if ((iam_all >> r) & 1u)
                rowmask |= 1u << ((r & 3) + ((r >> 2) << 3) + (hi << 2));
        if ((lane == 0 || lane == 32) && rowmask)
            atomicOr(&imask[(ti << 1) + wr], rowmask);

        if (anchor_j) {
            const unsigned long long b0 = __ballot(jany0 != 0);
            const uint_t m0 = (uint_t)b0 | (uint_t)(b0 >> 32);
            if (lane == 0 && m0) atomicOr(&jmask[jb], m0);
            const unsigned long long b1 = __ballot(jany1 != 0);
            const uint_t m1 = (uint_t)b1 | (uint_t)(b1 >> 32);
            if (lane == 0 && m1) atomicOr(&jmask[jb + 1], m1);
        }
    }

#pragma unroll
    for (int off = 32; off; off >>= 1) {
        ts   += __shfl_down(ts, off);
        ns   += __shfl_down(ns, off);
        cntf += __shfl_down(cntf, off);
    }
    if (lane == 0) wpart[wave] = make_float4(ts, ns, cntf, 0.f);
    __syncthreads();
    if (t == 0) {
        float4 s = wpart[0];
        s.x += wpart[1].x + wpart[2].x + wpart[3].x;
        s.y += wpart[1].y + wpart[2].y + wpart[3].y;
        s.z += wpart[1].z + wpart[2].z + wpart[3].z;
        partial[blockIdx.x] = s;
    }

    // -------- last-block-done fused finalize (G16: fence + device atomic) --
    __threadfence();                     // release our partial/mask writes
    if (t == 0)
        lastflag = (atomicAdd(counter, 1u) == NBLK - 1) ? 1u : 0u;
    __syncthreads();
    if (lastflag) {
        __threadfence();                 // acquire others' writes

        double fts = 0.0, fns = 0.0, fcnt = 0.0, fps = 0.0;
        uint_t zc = 0;
        for (int idx = t; idx < NBLK; idx += 256) {
            const float4 p = partial[idx];
            fts += (double)p.x; fns += (double)p.y; fcnt += (double)p.z;
        }
        if (t < 256) fps = (double)posp[t];
        if (t < 128) zc = 32u - (uint_t)__popc(imask[t] | jmask[t]);

#pragma unroll
        for (int off = 32; off; off >>= 1) {
            fts  += __shfl_down(fts, off);
            fns  += __shfl_down(fns, off);
            fcnt += __shfl_down(fcnt, off);
            fps  += __shfl_down(fps, off);
            zc   += __shfl_down(zc, off);
        }
        __shared__ double f0[4], f1[4], f2[4], f3[4];
        __shared__ uint_t f4[4];
        if (lane == 0) { f0[wave]=fts; f1[wave]=fns; f2[wave]=fcnt; f3[wave]=fps; f4[wave]=zc; }
        __syncthreads();
        if (t == 0) {
            double a0=0, a1=0, a2=0, a3=0; uint_t a4=0;
#pragma unroll
            for (int w = 0; w < 4; ++w) { a0+=f0[w]; a1+=f1[w]; a2+=f2[w]; a3+=f3[w]; a4+=f4[w]; }
            out[0] = (float)(a2 > 0.0 ? a0 / a2 : 0.0);
            out[1] = (float)((double)a4 / (double)NROWS);
            out[2] = (float)(a3 / ((double)NROWS * 3.0));
            out[3] = (float)(a1 / ((double)NROWS * (double)(NROWS - KCLS)));
        }
    }
}

extern "C" void kernel_launch(void* const* d_in, const int* in_sizes, int n_in,
                              void* d_out, int out_size, void* d_ws, size_t ws_size,
                              hipStream_t stream)
{
    const float* x = (const float*)d_in[0];
    float* out = (float*)d_out;
    char* ws = (char*)d_ws;

    // imask 512 | jmask 512 | counter 64 | posp 1024 | spd 64K | partial | xf
    uint_t*   imask   = (uint_t*)(ws + 0);
    uint_t*   jmask   = (uint_t*)(ws + 512);
    uint_t*   counter = (uint_t*)(ws + 1024);
    float*    posp    = (float*)(ws + 1088);
    float4*   spd     = (float4*)(ws + 2112);
    float4*   partial = (float4*)(ws + 2112 + 65536);
    ushort_t* xf      = (ushort_t*)(ws + 2112 + 65536 + 16896);

    k_prep<<<256, 256, 0, stream>>>(x, spd, xf, imask, jmask, counter, posp);
    k_tiles<<<NBLK, 256, 0, stream>>>(xf, spd, imask, jmask, partial,
                                      counter, posp, out);
}

// Round 13
// 114.968 us; speedup vs baseline: 1.4279x; 1.4279x over previous
//
#include <hip/hip_runtime.h>

#define NROWS 4096
#define DIM   128
#define KCLS  4
#define NBLK  1056               // sum_{tJ=0..31} (2*tJ+2) = 8*132
#define MARGIN_F 0.02f
#define EPS_F    1e-12f

typedef unsigned short ushort_t;
typedef unsigned int   uint_t;
typedef __attribute__((ext_vector_type(8)))  short bf16x8;
typedef __attribute__((ext_vector_type(16))) float f32x16;

__device__ __forceinline__ ushort_t rne_bf16(float v, float& back) {
    uint_t u = __float_as_uint(v);
    uint_t r = (u + 0x7fffu + ((u >> 16) & 1u)) >> 16;
    back = __uint_as_float(r << 16);
    return (ushort_t)r;
}

__device__ __forceinline__ bf16x8 pack8(const ushort_t* h) {
    bf16x8 v;
#pragma unroll
    for (int e = 0; e < 8; ++e) v[e] = (short)h[e];
    return v;
}

__device__ __forceinline__ float fsqrt(float x) {
    float r;
    asm("v_sqrt_f32 %0, %1" : "=v"(r) : "v"(x));
    return r;
}

// blocks ordered tJ ascending, ti in 0..2tJ+1; start(tJ)=tJ*(tJ+1)
__device__ __forceinline__ void blk_decode(int bid, int& ti, int& tJ) {
    tJ = (int)((sqrtf((float)(4 * bid + 1)) - 1.0f) * 0.5f);
    while ((tJ + 1) * (tJ + 2) <= bid) ++tJ;
    while (tJ * (tJ + 1) > bid) --tJ;
    ti = bid - tJ * (tJ + 1);
}

// ---------------- kernel 1: wave-per-class prep (validated R9/R10) ----------
__global__ __launch_bounds__(256) void k_prep(
    const float* __restrict__ x,
    float4* __restrict__ spd,
    ushort_t* __restrict__ xf,
    uint_t* __restrict__ imask, uint_t* __restrict__ jmask,
    float* __restrict__ posp)
{
    if (blockIdx.x == 0) {
        const int tt = threadIdx.x;
        if (tt < 128) imask[tt] = 0u; else jmask[tt - 128] = 0u;
    }
    const int wave = threadIdx.x >> 6, lane = threadIdx.x & 63;
    const int cls  = (blockIdx.x << 2) + wave;
    const int r0   = lane >> 4;
    const int cseg = lane & 15;
    const int row  = (cls << 2) + r0;

    const float4* rp = (const float4*)(x + (size_t)row * DIM + (cseg << 3));
    const float4 v0 = rp[0], v1 = rp[1];
    float vs[8] = {v0.x, v0.y, v0.z, v0.w, v1.x, v1.y, v1.z, v1.w};

    float sq = 0.f;
#pragma unroll
    for (int e = 0; e < 8; ++e) sq = fmaf(vs[e], vs[e], sq);
#pragma unroll
    for (int off = 1; off < 16; off <<= 1) sq += __shfl_xor(sq, off, 16);

    float sq4[4];
#pragma unroll
    for (int s = 0; s < 4; ++s) sq4[s] = __shfl(sq, (s << 4) | cseg);

    float dl[3];
#pragma unroll
    for (int delta = 1; delta <= 3; ++delta) {
        const int p = r0 ^ delta;
        float dot = 0.f;
#pragma unroll
        for (int e = 0; e < 8; ++e) {
            const float o = __shfl(vs[e], (p << 4) | cseg);
            dot = fmaf(vs[e], o, dot);
        }
#pragma unroll
        for (int off = 1; off < 16; off <<= 1) dot += __shfl_xor(dot, off, 16);
        dl[delta - 1] = fsqrt(fmaxf(sq4[r0] + sq4[p] - 2.f * dot, EPS_F));
    }
    float po[3];
#pragma unroll
    for (int o = 0; o < 3; ++o) {
        const int s = o + (o >= r0 ? 1 : 0);
        const int d = r0 ^ s;
        po[o] = (d == 1) ? dl[0] : (d == 2) ? dl[1] : dl[2];
    }
    if (cseg == 0) spd[row] = make_float4(sq4[r0], po[0], po[1], po[2]);

    // per-block positive-distance partial (slims k_final)
    float ppart = (cseg == 0) ? (po[0] + po[1] + po[2]) : 0.f;
#pragma unroll
    for (int off = 32; off; off >>= 1) ppart += __shfl_down(ppart, off);
    __shared__ float pblk[4];
    if (lane == 0) pblk[wave] = ppart;
    __syncthreads();
    if (threadIdx.x == 0)
        posp[blockIdx.x] = pblk[0] + pblk[1] + pblk[2] + pblk[3];

    ushort_t hs[8], ls[8];
#pragma unroll
    for (int e = 0; e < 8; ++e) {
        float back, d_;
        hs[e] = rne_bf16(vs[e], back);
        ls[e] = rne_bf16(vs[e] - back, d_);
    }
    const int band = row >> 5, L = row & 31, cb = cseg >> 1, sf = cseg & 1;
    ushort_t* dst = xf + ((size_t)((band << 3) + cb) << 1) * 512
                       + (((sf << 5) + L) << 3);
    *(bf16x8*)dst         = pack8(hs);
    *(bf16x8*)(dst + 512) = pack8(ls);
}

// ---------------- kernel 2: MFMA Gram + fused hinge (R10 + T1 swizzle) -----
__global__ __launch_bounds__(256, 4) void k_tiles(
    const ushort_t* __restrict__ xf,
    const float4* __restrict__ spd,
    uint_t* __restrict__ imask, uint_t* __restrict__ jmask,
    float4* __restrict__ partial)
{
    // T1: XCD-aware bijective swizzle (1056 = 8 XCDs x 132). Consecutive
    // logical tiles (which share the tJ panel's j-fragments) land on the
    // SAME XCD's L2 instead of round-robining across all 8.
    const int lbid = ((blockIdx.x & 7) * 132) + ((int)blockIdx.x >> 3);
    int ti, tJ;
    blk_decode(lbid, ti, tJ);

    const int t = threadIdx.x, wave = t >> 6, lane = t & 63;
    const int wr = wave >> 1, wc = wave & 1;
    const int col = lane & 31, hi = lane >> 5;
    const int ibase = ti << 6;
    const int tj64 = (tJ << 1) + wc;
    const bool active   = (tj64 >= ti);
    const bool anchor_j = (tj64 > ti);
    const int jb  = (tJ << 2) + (wc << 1);
    const int jg0 = (jb << 5) + col;
    const int jg1 = jg0 + 32;

    __shared__ float4 spd_i[64];
    __shared__ float4 wpart[4];

    // T14: issue row-spd load now, consume after the MFMA phase
    float4 myspd;
    if (t < 64) myspd = spd[ibase + t];
    const float4 sj0 = spd[jg0];
    const float4 sj1 = spd[jg1];

    const ushort_t* pa  = xf + (size_t)((ti << 1) + wr) * 8192 + lane * 8;
    const ushort_t* pb0 = xf + (size_t)jb * 8192 + lane * 8;
    const ushort_t* pb1 = pb0 + 8192;

    f32x16 acc0, acc1;
#pragma unroll
    for (int r = 0; r < 16; ++r) { acc0[r] = 0.f; acc1[r] = 0.f; }

#pragma unroll
    for (int c = 0; c < 8; ++c) {
        const bf16x8 ah  = *(const bf16x8*)(pa  + c * 1024);
        const bf16x8 al  = *(const bf16x8*)(pa  + c * 1024 + 512);
        const bf16x8 b0h = *(const bf16x8*)(pb0 + c * 1024);
        const bf16x8 b0l = *(const bf16x8*)(pb0 + c * 1024 + 512);
        const bf16x8 b1h = *(const bf16x8*)(pb1 + c * 1024);
        const bf16x8 b1l = *(const bf16x8*)(pb1 + c * 1024 + 512);
        acc0 = __builtin_amdgcn_mfma_f32_32x32x16_bf16(ah, b0h, acc0, 0, 0, 0);
        acc1 = __builtin_amdgcn_mfma_f32_32x32x16_bf16(ah, b1h, acc1, 0, 0, 0);
        acc0 = __builtin_amdgcn_mfma_f32_32x32x16_bf16(ah, b0l, acc0, 0, 0, 0);
        acc1 = __builtin_amdgcn_mfma_f32_32x32x16_bf16(ah, b1l, acc1, 0, 0, 0);
        acc0 = __builtin_amdgcn_mfma_f32_32x32x16_bf16(al, b0h, acc0, 0, 0, 0);
        acc1 = __builtin_amdgcn_mfma_f32_32x32x16_bf16(al, b1h, acc1, 0, 0, 0);
    }

    if (t < 64) spd_i[t] = myspd;
    __syncthreads();

    float ts = 0.f, ns = 0.f, cntf = 0.f;
    uint_t iam = 0, jany0 = 0, jany1 = 0;

    if (active) {
        const int jcls0 = jg0 >> 2, jcls1 = jg1 >> 2;
        const float nsw = anchor_j ? 2.f : 1.f;
#pragma unroll
        for (int r = 0; r < 16; ++r) {
            const int src = (r & 3) + ((r >> 2) << 3) + (hi << 2);
            const float4 si = spd_i[(wr << 5) + src];
            const int icls = (ibase + (wr << 5) + src) >> 2;
            {   // band 0
                const float dd = fsqrt(fmaxf(si.x + sj0.x - 2.f * acc0[r], EPS_F));
                const bool skip = !anchor_j && (icls == jcls0);
                if (!skip) {
                    ns += nsw * dd;
                    uint_t v = 0; float h;
                    h = si.y + MARGIN_F - dd; if (h > 0.f) { ts += h; cntf += 1.f; v = 1u; }
                    h = si.z + MARGIN_F - dd; if (h > 0.f) { ts += h; cntf += 1.f; v = 1u; }
                    h = si.w + MARGIN_F - dd; if (h > 0.f) { ts += h; cntf += 1.f; v = 1u; }
                    iam |= v << r;
                    if (anchor_j) {
                        h = sj0.y + MARGIN_F - dd; if (h > 0.f) { ts += h; cntf += 1.f; jany0 = 1u; }
                        h = sj0.z + MARGIN_F - dd; if (h > 0.f) { ts += h; cntf += 1.f; jany0 = 1u; }
                        h = sj0.w + MARGIN_F - dd; if (h > 0.f) { ts += h; cntf += 1.f; jany0 = 1u; }
                    }
                }
            }
            {   // band 1
                const float dd = fsqrt(fmaxf(si.x + sj1.x - 2.f * acc1[r], EPS_F));
                const bool skip = !anchor_j && (icls == jcls1);
                if (!skip) {
                    ns += nsw * dd;
                    uint_t v = 0; float h;
                    h = si.y + MARGIN_F - dd; if (h > 0.f) { ts += h; cntf += 1.f; v = 1u; }
                    h = si.z + MARGIN_F - dd; if (h > 0.f) { ts += h; cntf += 1.f; v = 1u; }
                    h = si.w + MARGIN_F - dd; if (h > 0.f) { ts += h; cntf += 1.f; v = 1u; }
                    iam |= v << r;
                    if (anchor_j) {
                        h = sj1.y + MARGIN_F - dd; if (h > 0.f) { ts += h; cntf += 1.f; jany1 = 1u; }
                        h = sj1.z + MARGIN_F - dd; if (h > 0.f) { ts += h; cntf += 1.f; jany1 = 1u; }
                        h = sj1.w + MARGIN_F - dd; if (h > 0.f) { ts += h; cntf += 1.f; jany1 = 1u; }
                    }
                }
            }
        }

        uint_t iam_all = iam;
#pragma unroll
        for (int off = 1; off < 32; off <<= 1)
            iam_all |= __shfl_xor(iam_all, off);
        uint_t rowmask = 0;
#pragma unroll
        for (int r = 0; r < 16; ++r)
            if ((iam_all >> r) & 1u)
                rowmask |= 1u << ((r & 3) + ((r >> 2) << 3) + (hi << 2));
        if ((lane == 0 || lane == 32) && rowmask)
            atomicOr(&imask[(ti << 1) + wr], rowmask);

        if (anchor_j) {
            const unsigned long long b0 = __ballot(jany0 != 0);
            const uint_t m0 = (uint_t)b0 | (uint_t)(b0 >> 32);
            if (lane == 0 && m0) atomicOr(&jmask[jb], m0);
            const unsigned long long b1 = __ballot(jany1 != 0);
            const uint_t m1 = (uint_t)b1 | (uint_t)(b1 >> 32);
            if (lane == 0 && m1) atomicOr(&jmask[jb + 1], m1);
        }
    }

#pragma unroll
    for (int off = 32; off; off >>= 1) {
        ts   += __shfl_down(ts, off);
        ns   += __shfl_down(ns, off);
        cntf += __shfl_down(cntf, off);
    }
    if (lane == 0) wpart[wave] = make_float4(ts, ns, cntf, 0.f);
    __syncthreads();
    if (t == 0) {
        float4 s = wpart[0];
        s.x += wpart[1].x + wpart[2].x + wpart[3].x;
        s.y += wpart[1].y + wpart[2].y + wpart[3].y;
        s.z += wpart[1].z + wpart[2].z + wpart[3].z;
        partial[lbid] = s;
    }
}

// ---------------- kernel 3: finalize (slim: 256 threads) ----------------
__global__ void k_final(const uint_t* __restrict__ imask,
                        const uint_t* __restrict__ jmask,
                        const float4* __restrict__ partial,
                        const float* __restrict__ posp,
                        float* __restrict__ out)
{
    const int t = threadIdx.x;      // 256
    const int lane = t & 63, wave = t >> 6;
    double ts = 0.0, ns = 0.0, cnt = 0.0, ps = 0.0;
    uint_t zc = 0;

    for (int idx = t; idx < NBLK; idx += 256) {
        const float4 p = partial[idx];
        ts += (double)p.x; ns += (double)p.y; cnt += (double)p.z;
    }
    ps = (double)posp[t];
    if (t < 128) zc = 32u - (uint_t)__popc(imask[t] | jmask[t]);

#pragma unroll
    for (int off = 32; off; off >>= 1) {
        ts  += __shfl_down(ts, off);
        ns  += __shfl_down(ns, off);
        cnt += __shfl_down(cnt, off);
        ps  += __shfl_down(ps, off);
        zc  += __shfl_down(zc, off);
    }
    __shared__ double s0[4], s1[4], s2[4], s3[4];
    __shared__ uint_t s4[4];
    if (lane == 0) { s0[wave]=ts; s1[wave]=ns; s2[wave]=cnt; s3[wave]=ps; s4[wave]=zc; }
    __syncthreads();
    if (t == 0) {
        double a0=0, a1=0, a2=0, a3=0; uint_t a4=0;
#pragma unroll
        for (int w = 0; w < 4; ++w) { a0+=s0[w]; a1+=s1[w]; a2+=s2[w]; a3+=s3[w]; a4+=s4[w]; }
        out[0] = (float)(a2 > 0.0 ? a0 / a2 : 0.0);
        out[1] = (float)((double)a4 / (double)NROWS);
        out[2] = (float)(a3 / ((double)NROWS * 3.0));
        out[3] = (float)(a1 / ((double)NROWS * (double)(NROWS - KCLS)));
    }
}

extern "C" void kernel_launch(void* const* d_in, const int* in_sizes, int n_in,
                              void* d_out, int out_size, void* d_ws, size_t ws_size,
                              hipStream_t stream)
{
    const float* x = (const float*)d_in[0];
    float* out = (float*)d_out;
    char* ws = (char*)d_ws;

    // imask 512 | jmask 512 | posp 1024 | spd 64K | partial NBLK*16 | xf 2MB
    uint_t*   imask   = (uint_t*)(ws + 0);
    uint_t*   jmask   = (uint_t*)(ws + 512);
    float*    posp    = (float*)(ws + 1024);
    float4*   spd     = (float4*)(ws + 2048);
    float4*   partial = (float4*)(ws + 2048 + 65536);
    ushort_t* xf      = (ushort_t*)(ws + 2048 + 65536 + 16896);

    k_prep<<<256, 256, 0, stream>>>(x, spd, xf, imask, jmask, posp);
    k_tiles<<<NBLK, 256, 0, stream>>>(xf, spd, imask, jmask, partial);
    k_final<<<1, 256, 0, stream>>>(imask, jmask, partial, posp, out);
}

// Round 14
// 113.183 us; speedup vs baseline: 1.4505x; 1.0158x over previous
//
#include <hip/hip_runtime.h>

#define NROWS 4096
#define DIM   128
#define KCLS  4
#define NBLK  1056               // sum_{tJ=0..31} (2*tJ+2) = 8*132
#define MARGIN_F 0.02f
#define EPS_F    1e-12f

typedef unsigned short ushort_t;
typedef unsigned int   uint_t;
typedef __attribute__((ext_vector_type(8)))  short bf16x8;
typedef __attribute__((ext_vector_type(16))) float f32x16;

__device__ __forceinline__ ushort_t rne_bf16(float v, float& back) {
    uint_t u = __float_as_uint(v);
    uint_t r = (u + 0x7fffu + ((u >> 16) & 1u)) >> 16;
    back = __uint_as_float(r << 16);
    return (ushort_t)r;
}

__device__ __forceinline__ bf16x8 pack8(const ushort_t* h) {
    bf16x8 v;
#pragma unroll
    for (int e = 0; e < 8; ++e) v[e] = (short)h[e];
    return v;
}

__device__ __forceinline__ float fsqrt(float x) {
    float r;
    asm("v_sqrt_f32 %0, %1" : "=v"(r) : "v"(x));
    return r;
}

__device__ __forceinline__ void gload_lds16(const void* g, void* l) {
    __builtin_amdgcn_global_load_lds(
        (const __attribute__((address_space(1))) unsigned int*)g,
        (__attribute__((address_space(3))) unsigned int*)l, 16, 0, 0);
}

// blocks ordered tJ ascending, ti in 0..2tJ+1; start(tJ)=tJ*(tJ+1)
__device__ __forceinline__ void blk_decode(int bid, int& ti, int& tJ) {
    tJ = (int)((sqrtf((float)(4 * bid + 1)) - 1.0f) * 0.5f);
    while ((tJ + 1) * (tJ + 2) <= bid) ++tJ;
    while (tJ * (tJ + 1) > bid) --tJ;
    ti = bid - tJ * (tJ + 1);
}

// ---------------- kernel 1: wave-per-class prep (validated R9/R10/R13) ------
__global__ __launch_bounds__(256) void k_prep(
    const float* __restrict__ x,
    float4* __restrict__ spd,
    ushort_t* __restrict__ xf,
    uint_t* __restrict__ imask, uint_t* __restrict__ jmask,
    float* __restrict__ posp)
{
    if (blockIdx.x == 0) {
        const int tt = threadIdx.x;
        if (tt < 128) imask[tt] = 0u; else jmask[tt - 128] = 0u;
    }
    const int wave = threadIdx.x >> 6, lane = threadIdx.x & 63;
    const int cls  = (blockIdx.x << 2) + wave;
    const int r0   = lane >> 4;
    const int cseg = lane & 15;
    const int row  = (cls << 2) + r0;

    const float4* rp = (const float4*)(x + (size_t)row * DIM + (cseg << 3));
    const float4 v0 = rp[0], v1 = rp[1];
    float vs[8] = {v0.x, v0.y, v0.z, v0.w, v1.x, v1.y, v1.z, v1.w};

    float sq = 0.f;
#pragma unroll
    for (int e = 0; e < 8; ++e) sq = fmaf(vs[e], vs[e], sq);
#pragma unroll
    for (int off = 1; off < 16; off <<= 1) sq += __shfl_xor(sq, off, 16);

    float sq4[4];
#pragma unroll
    for (int s = 0; s < 4; ++s) sq4[s] = __shfl(sq, (s << 4) | cseg);

    float dl[3];
#pragma unroll
    for (int delta = 1; delta <= 3; ++delta) {
        const int p = r0 ^ delta;
        float dot = 0.f;
#pragma unroll
        for (int e = 0; e < 8; ++e) {
            const float o = __shfl(vs[e], (p << 4) | cseg);
            dot = fmaf(vs[e], o, dot);
        }
#pragma unroll
        for (int off = 1; off < 16; off <<= 1) dot += __shfl_xor(dot, off, 16);
        dl[delta - 1] = fsqrt(fmaxf(sq4[r0] + sq4[p] - 2.f * dot, EPS_F));
    }
    float po[3];
#pragma unroll
    for (int o = 0; o < 3; ++o) {
        const int s = o + (o >= r0 ? 1 : 0);
        const int d = r0 ^ s;
        po[o] = (d == 1) ? dl[0] : (d == 2) ? dl[1] : dl[2];
    }
    if (cseg == 0) spd[row] = make_float4(sq4[r0], po[0], po[1], po[2]);

    float ppart = (cseg == 0) ? (po[0] + po[1] + po[2]) : 0.f;
#pragma unroll
    for (int off = 32; off; off >>= 1) ppart += __shfl_down(ppart, off);
    __shared__ float pblk[4];
    if (lane == 0) pblk[wave] = ppart;
    __syncthreads();
    if (threadIdx.x == 0)
        posp[blockIdx.x] = pblk[0] + pblk[1] + pblk[2] + pblk[3];

    ushort_t hs[8], ls[8];
#pragma unroll
    for (int e = 0; e < 8; ++e) {
        float back, d_;
        hs[e] = rne_bf16(vs[e], back);
        ls[e] = rne_bf16(vs[e] - back, d_);
    }
    const int band = row >> 5, L = row & 31, cb = cseg >> 1, sf = cseg & 1;
    ushort_t* dst = xf + ((size_t)((band << 3) + cb) << 1) * 512
                       + (((sf << 5) + L) << 3);
    *(bf16x8*)dst         = pack8(hs);
    *(bf16x8*)(dst + 512) = pack8(ls);
}

// ---------------- kernel 2: LDS-staged MFMA Gram + fused hinge -------------
// One change vs R13: the 6 fragment bands (48 KB) are staged to LDS k-major
// via global_load_lds (one vmcnt drain), MFMA loop reads pure LDS
// (32 lanes x consecutive 16B -> 2-way bank aliasing = free, m136).
__global__ __launch_bounds__(256, 3) void k_tiles(
    const ushort_t* __restrict__ xf,
    const float4* __restrict__ spd,
    uint_t* __restrict__ imask, uint_t* __restrict__ jmask,
    float4* __restrict__ partial)
{
    const int lbid = ((blockIdx.x & 7) * 132) + ((int)blockIdx.x >> 3);
    int ti, tJ;
    blk_decode(lbid, ti, tJ);

    const int t = threadIdx.x, wave = t >> 6, lane = t & 63;
    const int wr = wave >> 1, wc = wave & 1;
    const int col = lane & 31, hi = lane >> 5;
    const int ibase = ti << 6;
    const int tj64 = (tJ << 1) + wc;
    const bool active   = (tj64 >= ti);
    const bool anchor_j = (tj64 > ti);
    const int jb  = (tJ << 2) + (wc << 1);
    const int jg0 = (jb << 5) + col;
    const int jg1 = jg0 + 32;

    __shared__ ushort_t frag[12 * 512 * 8];   // [bp][s][row] 16B units, 48 KB
    __shared__ float4 spd_i[64];
    __shared__ float4 wpart[4];

    // early: spd loads (latency hides under staging)
    float4 myspd;
    if (t < 64) myspd = spd[ibase + t];
    const float4 sj0 = spd[jg0];
    const float4 sj1 = spd[jg1];

    // ---- stage 6 bands x 2 planes, k-major: LDS unit u = bp*512 + s*32+row.
    // source short-offset = gband*8192 + (s>>1)*1024 + p*512 + (s&1)*256 + row*8
    int gband[6];
    gband[0] = (ti << 1);     gband[1] = (ti << 1) + 1;
    gband[2] = (tJ << 2);     gband[3] = (tJ << 2) + 1;
    gband[4] = (tJ << 2) + 2; gband[5] = (tJ << 2) + 3;

#pragma unroll
    for (int it = 0; it < 24; ++it) {
        const int ub = it * 256 + (wave << 6);      // wave-uniform base unit
        const int u  = ub + lane;
        const int bp = u >> 9, rem = u & 511;
        const int s = rem >> 5, row = rem & 31;
        const size_t goff = (size_t)gband[bp >> 1] * 8192
                          + ((s >> 1) << 10) + ((bp & 1) << 9)
                          + ((s & 1) << 8) + (row << 3);
        gload_lds16(xf + goff, &frag[(size_t)ub << 3]);
    }
    if (t < 64) spd_i[t] = myspd;
    __syncthreads();     // compiler inserts vmcnt(0) drain here

    // ---- MFMA loop from LDS (conflict-free k-major reads) ----
    const int bpA = wr << 1;            // A band-pair (h, l = +1)
    const int bpB0 = 4 + (wc << 2);     // j-band0 pair
    const int bpB1 = 6 + (wc << 2);     // j-band1 pair

    f32x16 acc0, acc1;
#pragma unroll
    for (int r = 0; r < 16; ++r) { acc0[r] = 0.f; acc1[r] = 0.f; }

#pragma unroll
    for (int c = 0; c < 8; ++c) {
        const int s = (c << 1) + hi;
        const int so = (s << 5) + col;
        const bf16x8 ah  = *(const bf16x8*)&frag[(((bpA     ) << 9) + so) << 3];
        const bf16x8 al  = *(const bf16x8*)&frag[(((bpA  + 1) << 9) + so) << 3];
        const bf16x8 b0h = *(const bf16x8*)&frag[(((bpB0    ) << 9) + so) << 3];
        const bf16x8 b0l = *(const bf16x8*)&frag[(((bpB0 + 1) << 9) + so) << 3];
        const bf16x8 b1h = *(const bf16x8*)&frag[(((bpB1    ) << 9) + so) << 3];
        const bf16x8 b1l = *(const bf16x8*)&frag[(((bpB1 + 1) << 9) + so) << 3];
        acc0 = __builtin_amdgcn_mfma_f32_32x32x16_bf16(ah, b0h, acc0, 0, 0, 0);
        acc1 = __builtin_amdgcn_mfma_f32_32x32x16_bf16(ah, b1h, acc1, 0, 0, 0);
        acc0 = __builtin_amdgcn_mfma_f32_32x32x16_bf16(ah, b0l, acc0, 0, 0, 0);
        acc1 = __builtin_amdgcn_mfma_f32_32x32x16_bf16(ah, b1l, acc1, 0, 0, 0);
        acc0 = __builtin_amdgcn_mfma_f32_32x32x16_bf16(al, b0h, acc0, 0, 0, 0);
        acc1 = __builtin_amdgcn_mfma_f32_32x32x16_bf16(al, b1h, acc1, 0, 0, 0);
    }

    // ---------------- epilogue (validated R10/R13 form) ----------------
    float ts = 0.f, ns = 0.f, cntf = 0.f;
    uint_t iam = 0, jany0 = 0, jany1 = 0;

    if (active) {
        const int jcls0 = jg0 >> 2, jcls1 = jg1 >> 2;
        const float nsw = anchor_j ? 2.f : 1.f;
#pragma unroll
        for (int r = 0; r < 16; ++r) {
            const int src = (r & 3) + ((r >> 2) << 3) + (hi << 2);
            const float4 si = spd_i[(wr << 5) + src];
            const int icls = (ibase + (wr << 5) + src) >> 2;
            {   // band 0
                const float dd = fsqrt(fmaxf(si.x + sj0.x - 2.f * acc0[r], EPS_F));
                const bool skip = !anchor_j && (icls == jcls0);
                if (!skip) {
                    ns += nsw * dd;
                    uint_t v = 0; float h;
                    h = si.y + MARGIN_F - dd; if (h > 0.f) { ts += h; cntf += 1.f; v = 1u; }
                    h = si.z + MARGIN_F - dd; if (h > 0.f) { ts += h; cntf += 1.f; v = 1u; }
                    h = si.w + MARGIN_F - dd; if (h > 0.f) { ts += h; cntf += 1.f; v = 1u; }
                    iam |= v << r;
                    if (anchor_j) {
                        h = sj0.y + MARGIN_F - dd; if (h > 0.f) { ts += h; cntf += 1.f; jany0 = 1u; }
                        h = sj0.z + MARGIN_F - dd; if (h > 0.f) { ts += h; cntf += 1.f; jany0 = 1u; }
                        h = sj0.w + MARGIN_F - dd; if (h > 0.f) { ts += h; cntf += 1.f; jany0 = 1u; }
                    }
                }
            }
            {   // band 1
                const float dd = fsqrt(fmaxf(si.x + sj1.x - 2.f * acc1[r], EPS_F));
                const bool skip = !anchor_j && (icls == jcls1);
                if (!skip) {
                    ns += nsw * dd;
                    uint_t v = 0; float h;
                    h = si.y + MARGIN_F - dd; if (h > 0.f) { ts += h; cntf += 1.f; v = 1u; }
                    h = si.z + MARGIN_F - dd; if (h > 0.f) { ts += h; cntf += 1.f; v = 1u; }
                    h = si.w + MARGIN_F - dd; if (h > 0.f) { ts += h; cntf += 1.f; v = 1u; }
                    iam |= v << r;
                    if (anchor_j) {
                        h = sj1.y + MARGIN_F - dd; if (h > 0.f) { ts += h; cntf += 1.f; jany1 = 1u; }
                        h = sj1.z + MARGIN_F - dd; if (h > 0.f) { ts += h; cntf += 1.f; jany1 = 1u; }
                        h = sj1.w + MARGIN_F - dd; if (h > 0.f) { ts += h; cntf += 1.f; jany1 = 1u; }
                    }
                }
            }
        }

        uint_t iam_all = iam;
#pragma unroll
        for (int off = 1; off < 32; off <<= 1)
            iam_all |= __shfl_xor(iam_all, off);
        uint_t rowmask = 0;
#pragma unroll
        for (int r = 0; r < 16; ++r)
            if ((iam_all >> r) & 1u)
                rowmask |= 1u << ((r & 3) + ((r >> 2) << 3) + (hi << 2));
        if ((lane == 0 || lane == 32) && rowmask)
            atomicOr(&imask[(ti << 1) + wr], rowmask);

        if (anchor_j) {
            const unsigned long long b0 = __ballot(jany0 != 0);
            const uint_t m0 = (uint_t)b0 | (uint_t)(b0 >> 32);
            if (lane == 0 && m0) atomicOr(&jmask[jb], m0);
            const unsigned long long b1 = __ballot(jany1 != 0);
            const uint_t m1 = (uint_t)b1 | (uint_t)(b1 >> 32);
            if (lane == 0 && m1) atomicOr(&jmask[jb + 1], m1);
        }
    }

#pragma unroll
    for (int off = 32; off; off >>= 1) {
        ts   += __shfl_down(ts, off);
        ns   += __shfl_down(ns, off);
        cntf += __shfl_down(cntf, off);
    }
    if (lane == 0) wpart[wave] = make_float4(ts, ns, cntf, 0.f);
    __syncthreads();
    if (t == 0) {
        float4 s = wpart[0];
        s.x += wpart[1].x + wpart[2].x + wpart[3].x;
        s.y += wpart[1].y + wpart[2].y + wpart[3].y;
        s.z += wpart[1].z + wpart[2].z + wpart[3].z;
        partial[blockIdx.x] = s;
    }
}

// ---------------- kernel 3: finalize (slim) ----------------
__global__ void k_final(const uint_t* __restrict__ imask,
                        const uint_t* __restrict__ jmask,
                        const float4* __restrict__ partial,
                        const float* __restrict__ posp,
                        float* __restrict__ out)
{
    const int t = threadIdx.x;      // 256
    const int lane = t & 63, wave = t >> 6;
    double ts = 0.0, ns = 0.0, cnt = 0.0, ps = 0.0;
    uint_t zc = 0;

    for (int idx = t; idx < NBLK; idx += 256) {
        const float4 p = partial[idx];
        ts += (double)p.x; ns += (double)p.y; cnt += (double)p.z;
    }
    ps = (double)posp[t];
    if (t < 128) zc = 32u - (uint_t)__popc(imask[t] | jmask[t]);

#pragma unroll
    for (int off = 32; off; off >>= 1) {
        ts  += __shfl_down(ts, off);
        ns  += __shfl_down(ns, off);
        cnt += __shfl_down(cnt, off);
        ps  += __shfl_down(ps, off);
        zc  += __shfl_down(zc, off);
    }
    __shared__ double s0[4], s1[4], s2[4], s3[4];
    __shared__ uint_t s4[4];
    if (lane == 0) { s0[wave]=ts; s1[wave]=ns; s2[wave]=cnt; s3[wave]=ps; s4[wave]=zc; }
    __syncthreads();
    if (t == 0) {
        double a0=0, a1=0, a2=0, a3=0; uint_t a4=0;
#pragma unroll
        for (int w = 0; w < 4; ++w) { a0+=s0[w]; a1+=s1[w]; a2+=s2[w]; a3+=s3[w]; a4+=s4[w]; }
        out[0] = (float)(a2 > 0.0 ? a0 / a2 : 0.0);
        out[1] = (float)((double)a4 / (double)NROWS);
        out[2] = (float)(a3 / ((double)NROWS * 3.0));
        out[3] = (float)(a1 / ((double)NROWS * (double)(NROWS - KCLS)));
    }
}

extern "C" void kernel_launch(void* const* d_in, const int* in_sizes, int n_in,
                              void* d_out, int out_size, void* d_ws, size_t ws_size,
                              hipStream_t stream)
{
    const float* x = (const float*)d_in[0];
    float* out = (float*)d_out;
    char* ws = (char*)d_ws;

    // imask 512 | jmask 512 | posp 1024 | spd 64K | partial NBLK*16 | xf 2MB
    uint_t*   imask   = (uint_t*)(ws + 0);
    uint_t*   jmask   = (uint_t*)(ws + 512);
    float*    posp    = (float*)(ws + 1024);
    float4*   spd     = (float4*)(ws + 2048);
    float4*   partial = (float4*)(ws + 2048 + 65536);
    ushort_t* xf      = (ushort_t*)(ws + 2048 + 65536 + 16896);

    k_prep<<<256, 256, 0, stream>>>(x, spd, xf, imask, jmask, posp);
    k_tiles<<<NBLK, 256, 0, stream>>>(xf, spd, imask, jmask, partial);
    k_final<<<1, 256, 0, stream>>>(imask, jmask, partial, posp, out);
}

// Round 15
// 110.498 us; speedup vs baseline: 1.4857x; 1.0243x over previous
//
#include <hip/hip_runtime.h>

#define NROWS 4096
#define DIM   128
#define KCLS  4
#define NBLK  1056               // sum_{tJ=0..31} (2*tJ+2)
#define MARGIN_F 0.02f
#define EPS_F    1e-12f

typedef unsigned short ushort_t;
typedef unsigned int   uint_t;
typedef __attribute__((ext_vector_type(8)))  short bf16x8;
typedef __attribute__((ext_vector_type(16))) float f32x16;

__device__ __forceinline__ ushort_t rne_bf16(float v, float& back) {
    uint_t u = __float_as_uint(v);
    uint_t r = (u + 0x7fffu + ((u >> 16) & 1u)) >> 16;
    back = __uint_as_float(r << 16);
    return (ushort_t)r;
}

__device__ __forceinline__ bf16x8 pack8(const ushort_t* h) {
    bf16x8 v;
#pragma unroll
    for (int e = 0; e < 8; ++e) v[e] = (short)h[e];
    return v;
}

__device__ __forceinline__ float fsqrt(float x) {
    float r;
    asm("v_sqrt_f32 %0, %1" : "=v"(r) : "v"(x));
    return r;
}

// blocks ordered tJ ascending, ti in 0..2tJ+1; start(tJ)=tJ*(tJ+1)
__device__ __forceinline__ void blk_decode(int bid, int& ti, int& tJ) {
    tJ = (int)((sqrtf((float)(4 * bid + 1)) - 1.0f) * 0.5f);
    while ((tJ + 1) * (tJ + 2) <= bid) ++tJ;
    while (tJ * (tJ + 1) > bid) --tJ;
    ti = bid - tJ * (tJ + 1);
}

// ---------------- kernel 1: wave-per-class prep (validated) ----------------
__global__ __launch_bounds__(256) void k_prep(
    const float* __restrict__ x,
    float4* __restrict__ spd,
    ushort_t* __restrict__ xf,
    uint_t* __restrict__ imask, uint_t* __restrict__ jmask,
    float* __restrict__ posp)
{
    if (blockIdx.x == 0) {
        const int tt = threadIdx.x;
        if (tt < 128) imask[tt] = 0u; else jmask[tt - 128] = 0u;
    }
    const int wave = threadIdx.x >> 6, lane = threadIdx.x & 63;
    const int cls  = (blockIdx.x << 2) + wave;
    const int r0   = lane >> 4;
    const int cseg = lane & 15;
    const int row  = (cls << 2) + r0;

    const float4* rp = (const float4*)(x + (size_t)row * DIM + (cseg << 3));
    const float4 v0 = rp[0], v1 = rp[1];
    float vs[8] = {v0.x, v0.y, v0.z, v0.w, v1.x, v1.y, v1.z, v1.w};

    float sq = 0.f;
#pragma unroll
    for (int e = 0; e < 8; ++e) sq = fmaf(vs[e], vs[e], sq);
#pragma unroll
    for (int off = 1; off < 16; off <<= 1) sq += __shfl_xor(sq, off, 16);

    float sq4[4];
#pragma unroll
    for (int s = 0; s < 4; ++s) sq4[s] = __shfl(sq, (s << 4) | cseg);

    float dl[3];
#pragma unroll
    for (int delta = 1; delta <= 3; ++delta) {
        const int p = r0 ^ delta;
        float dot = 0.f;
#pragma unroll
        for (int e = 0; e < 8; ++e) {
            const float o = __shfl(vs[e], (p << 4) | cseg);
            dot = fmaf(vs[e], o, dot);
        }
#pragma unroll
        for (int off = 1; off < 16; off <<= 1) dot += __shfl_xor(dot, off, 16);
        dl[delta - 1] = fsqrt(fmaxf(sq4[r0] + sq4[p] - 2.f * dot, EPS_F));
    }
    float po[3];
#pragma unroll
    for (int o = 0; o < 3; ++o) {
        const int s = o + (o >= r0 ? 1 : 0);
        const int d = r0 ^ s;
        po[o] = (d == 1) ? dl[0] : (d == 2) ? dl[1] : dl[2];
    }
    if (cseg == 0) spd[row] = make_float4(sq4[r0], po[0], po[1], po[2]);

    float ppart = (cseg == 0) ? (po[0] + po[1] + po[2]) : 0.f;
#pragma unroll
    for (int off = 32; off; off >>= 1) ppart += __shfl_down(ppart, off);
    __shared__ float pblk[4];
    if (lane == 0) pblk[wave] = ppart;
    __syncthreads();
    if (threadIdx.x == 0)
        posp[blockIdx.x] = pblk[0] + pblk[1] + pblk[2] + pblk[3];

    ushort_t hs[8], ls[8];
#pragma unroll
    for (int e = 0; e < 8; ++e) {
        float back, d_;
        hs[e] = rne_bf16(vs[e], back);
        ls[e] = rne_bf16(vs[e] - back, d_);
    }
    const int band = row >> 5, L = row & 31, cb = cseg >> 1, sf = cseg & 1;
    ushort_t* dst = xf + ((size_t)((band << 3) + cb) << 1) * 512
                       + (((sf << 5) + L) << 3);
    *(bf16x8*)dst         = pack8(hs);
    *(bf16x8*)(dst + 512) = pack8(ls);
}

// ---------------- kernel 2: deep-prefetch MFMA Gram + fused hinge ----------
// One change vs R10: ALL 48 fragment loads issued into named registers before
// any MFMA (one vmcnt window instead of ~10 exposed latency windows).
// launch_bounds(256,1) gives the scheduler the full 256-VGPR budget so it
// does NOT sink the loads (R12's failure mode under (256,4)).
#define LDF(dst, base, off) dst = *(const bf16x8*)((base) + (off))

#define LDB(S, c) \
    LDF(aH##S, pa, (c) * 1024);  LDF(aL##S, pa, (c) * 1024 + 512); \
    LDF(bH##S, pb0, (c) * 1024); LDF(bL##S, pb0, (c) * 1024 + 512); \
    LDF(cH##S, pb1, (c) * 1024); LDF(cL##S, pb1, (c) * 1024 + 512);

#define MM(S) \
    acc0 = __builtin_amdgcn_mfma_f32_32x32x16_bf16(aH##S, bH##S, acc0, 0, 0, 0); \
    acc1 = __builtin_amdgcn_mfma_f32_32x32x16_bf16(aH##S, cH##S, acc1, 0, 0, 0); \
    acc0 = __builtin_amdgcn_mfma_f32_32x32x16_bf16(aH##S, bL##S, acc0, 0, 0, 0); \
    acc1 = __builtin_amdgcn_mfma_f32_32x32x16_bf16(aH##S, cL##S, acc1, 0, 0, 0); \
    acc0 = __builtin_amdgcn_mfma_f32_32x32x16_bf16(aL##S, bH##S, acc0, 0, 0, 0); \
    acc1 = __builtin_amdgcn_mfma_f32_32x32x16_bf16(aL##S, cH##S, acc1, 0, 0, 0);

__global__ __launch_bounds__(256, 1) void k_tiles(
    const ushort_t* __restrict__ xf,
    const float4* __restrict__ spd,
    uint_t* __restrict__ imask, uint_t* __restrict__ jmask,
    float4* __restrict__ partial)
{
    int ti, tJ;
    blk_decode((int)blockIdx.x, ti, tJ);

    const int t = threadIdx.x, wave = t >> 6, lane = t & 63;
    const int wr = wave >> 1, wc = wave & 1;
    const int col = lane & 31, hi = lane >> 5;
    const int ibase = ti << 6;
    const int tj64 = (tJ << 1) + wc;
    const bool active   = (tj64 >= ti);
    const bool anchor_j = (tj64 > ti);
    const int jb  = (tJ << 2) + (wc << 1);
    const int jg0 = (jb << 5) + col;
    const int jg1 = jg0 + 32;

    __shared__ float4 spd_i[64];
    __shared__ float4 wpart[4];

    float4 myspd;
    if (t < 64) myspd = spd[ibase + t];
    const float4 sj0 = spd[jg0];
    const float4 sj1 = spd[jg1];

    const ushort_t* pa  = xf + (size_t)((ti << 1) + wr) * 8192 + lane * 8;
    const ushort_t* pb0 = xf + (size_t)jb * 8192 + lane * 8;
    const ushort_t* pb1 = pb0 + 8192;

    f32x16 acc0, acc1;
#pragma unroll
    for (int r = 0; r < 16; ++r) { acc0[r] = 0.f; acc1[r] = 0.f; }

    bf16x8 aH0, aL0, bH0, bL0, cH0, cL0;
    bf16x8 aH1, aL1, bH1, bL1, cH1, cL1;
    bf16x8 aH2, aL2, bH2, bL2, cH2, cL2;
    bf16x8 aH3, aL3, bH3, bL3, cH3, cL3;
    bf16x8 aH4, aL4, bH4, bL4, cH4, cL4;
    bf16x8 aH5, aL5, bH5, bL5, cH5, cL5;
    bf16x8 aH6, aL6, bH6, bL6, cH6, cL6;
    bf16x8 aH7, aL7, bH7, bL7, cH7, cL7;

    // issue ALL 48 loads, then consume
    LDB(0, 0) LDB(1, 1) LDB(2, 2) LDB(3, 3)
    LDB(4, 4) LDB(5, 5) LDB(6, 6) LDB(7, 7)
    MM(0) MM(1) MM(2) MM(3) MM(4) MM(5) MM(6) MM(7)

    if (t < 64) spd_i[t] = myspd;
    __syncthreads();

    // ---------------- epilogue (validated R10/R13 form) ----------------
    float ts = 0.f, ns = 0.f, cntf = 0.f;
    uint_t iam = 0, jany0 = 0, jany1 = 0;

    if (active) {
        const int jcls0 = jg0 >> 2, jcls1 = jg1 >> 2;
        const float nsw = anchor_j ? 2.f : 1.f;
#pragma unroll
        for (int r = 0; r < 16; ++r) {
            const int src = (r & 3) + ((r >> 2) << 3) + (hi << 2);
            const float4 si = spd_i[(wr << 5) + src];
            const int icls = (ibase + (wr << 5) + src) >> 2;
            {   // band 0
                const float dd = fsqrt(fmaxf(si.x + sj0.x - 2.f * acc0[r], EPS_F));
                const bool skip = !anchor_j && (icls == jcls0);
                if (!skip) {
                    ns += nsw * dd;
                    uint_t v = 0; float h;
                    h = si.y + MARGIN_F - dd; if (h > 0.f) { ts += h; cntf += 1.f; v = 1u; }
                    h = si.z + MARGIN_F - dd; if (h > 0.f) { ts += h; cntf += 1.f; v = 1u; }
                    h = si.w + MARGIN_F - dd; if (h > 0.f) { ts += h; cntf += 1.f; v = 1u; }
                    iam |= v << r;
                    if (anchor_j) {
                        h = sj0.y + MARGIN_F - dd; if (h > 0.f) { ts += h; cntf += 1.f; jany0 = 1u; }
                        h = sj0.z + MARGIN_F - dd; if (h > 0.f) { ts += h; cntf += 1.f; jany0 = 1u; }
                        h = sj0.w + MARGIN_F - dd; if (h > 0.f) { ts += h; cntf += 1.f; jany0 = 1u; }
                    }
                }
            }
            {   // band 1
                const float dd = fsqrt(fmaxf(si.x + sj1.x - 2.f * acc1[r], EPS_F));
                const bool skip = !anchor_j && (icls == jcls1);
                if (!skip) {
                    ns += nsw * dd;
                    uint_t v = 0; float h;
                    h = si.y + MARGIN_F - dd; if (h > 0.f) { ts += h; cntf += 1.f; v = 1u; }
                    h = si.z + MARGIN_F - dd; if (h > 0.f) { ts += h; cntf += 1.f; v = 1u; }
                    h = si.w + MARGIN_F - dd; if (h > 0.f) { ts += h; cntf += 1.f; v = 1u; }
                    iam |= v << r;
                    if (anchor_j) {
                        h = sj1.y + MARGIN_F - dd; if (h > 0.f) { ts += h; cntf += 1.f; jany1 = 1u; }
                        h = sj1.z + MARGIN_F - dd; if (h > 0.f) { ts += h; cntf += 1.f; jany1 = 1u; }
                        h = sj1.w + MARGIN_F - dd; if (h > 0.f) { ts += h; cntf += 1.f; jany1 = 1u; }
                    }
                }
            }
        }

        uint_t iam_all = iam;
#pragma unroll
        for (int off = 1; off < 32; off <<= 1)
            iam_all |= __shfl_xor(iam_all, off);
        uint_t rowmask = 0;
#pragma unroll
        for (int r = 0; r < 16; ++r)
            if ((iam_all >> r) & 1u)
                rowmask |= 1u << ((r & 3) + ((r >> 2) << 3) + (hi << 2));
        if ((lane == 0 || lane == 32) && rowmask)
            atomicOr(&imask[(ti << 1) + wr], rowmask);

        if (anchor_j) {
            const unsigned long long b0 = __ballot(jany0 != 0);
            const uint_t m0 = (uint_t)b0 | (uint_t)(b0 >> 32);
            if (lane == 0 && m0) atomicOr(&jmask[jb], m0);
            const unsigned long long b1 = __ballot(jany1 != 0);
            const uint_t m1 = (uint_t)b1 | (uint_t)(b1 >> 32);
            if (lane == 0 && m1) atomicOr(&jmask[jb + 1], m1);
        }
    }

#pragma unroll
    for (int off = 32; off; off >>= 1) {
        ts   += __shfl_down(ts, off);
        ns   += __shfl_down(ns, off);
        cntf += __shfl_down(cntf, off);
    }
    if (lane == 0) wpart[wave] = make_float4(ts, ns, cntf, 0.f);
    __syncthreads();
    if (t == 0) {
        float4 s = wpart[0];
        s.x += wpart[1].x + wpart[2].x + wpart[3].x;
        s.y += wpart[1].y + wpart[2].y + wpart[3].y;
        s.z += wpart[1].z + wpart[2].z + wpart[3].z;
        partial[blockIdx.x] = s;
    }
}

// ---------------- kernel 3: finalize (slim) ----------------
__global__ void k_final(const uint_t* __restrict__ imask,
                        const uint_t* __restrict__ jmask,
                        const float4* __restrict__ partial,
                        const float* __restrict__ posp,
                        float* __restrict__ out)
{
    const int t = threadIdx.x;      // 256
    const int lane = t & 63, wave = t >> 6;
    double ts = 0.0, ns = 0.0, cnt = 0.0, ps = 0.0;
    uint_t zc = 0;

    for (int idx = t; idx < NBLK; idx += 256) {
        const float4 p = partial[idx];
        ts += (double)p.x; ns += (double)p.y; cnt += (double)p.z;
    }
    ps = (double)posp[t];
    if (t < 128) zc = 32u - (uint_t)__popc(imask[t] | jmask[t]);

#pragma unroll
    for (int off = 32; off; off >>= 1) {
        ts  += __shfl_down(ts, off);
        ns  += __shfl_down(ns, off);
        cnt += __shfl_down(cnt, off);
        ps  += __shfl_down(ps, off);
        zc  += __shfl_down(zc, off);
    }
    __shared__ double s0[4], s1[4], s2[4], s3[4];
    __shared__ uint_t s4[4];
    if (lane == 0) { s0[wave]=ts; s1[wave]=ns; s2[wave]=cnt; s3[wave]=ps; s4[wave]=zc; }
    __syncthreads();
    if (t == 0) {
        double a0=0, a1=0, a2=0, a3=0; uint_t a4=0;
#pragma unroll
        for (int w = 0; w < 4; ++w) { a0+=s0[w]; a1+=s1[w]; a2+=s2[w]; a3+=s3[w]; a4+=s4[w]; }
        out[0] = (float)(a2 > 0.0 ? a0 / a2 : 0.0);
        out[1] = (float)((double)a4 / (double)NROWS);
        out[2] = (float)(a3 / ((double)NROWS * 3.0));
        out[3] = (float)(a1 / ((double)NROWS * (double)(NROWS - KCLS)));
    }
}

extern "C" void kernel_launch(void* const* d_in, const int* in_sizes, int n_in,
                              void* d_out, int out_size, void* d_ws, size_t ws_size,
                              hipStream_t stream)
{
    const float* x = (const float*)d_in[0];
    float* out = (float*)d_out;
    char* ws = (char*)d_ws;

    // imask 512 | jmask 512 | posp 1024 | spd 64K | partial NBLK*16 | xf 2MB
    uint_t*   imask   = (uint_t*)(ws + 0);
    uint_t*   jmask   = (uint_t*)(ws + 512);
    float*    posp    = (float*)(ws + 1024);
    float4*   spd     = (float4*)(ws + 2048);
    float4*   partial = (float4*)(ws + 2048 + 65536);
    ushort_t* xf      = (ushort_t*)(ws + 2048 + 65536 + 16896);

    k_prep<<<256, 256, 0, stream>>>(x, spd, xf, imask, jmask, posp);
    k_tiles<<<NBLK, 256, 0, stream>>>(xf, spd, imask, jmask, partial);
    k_final<<<1, 256, 0, stream>>>(imask, jmask, partial, posp, out);
}